// Round 2
// baseline (38905.768 us; speedup 1.0000x reference)
//
#include <hip/hip_runtime.h>
#include <hip/hip_cooperative_groups.h>

namespace cg = cooperative_groups;

#define BB 64
#define TT 1000
#define II 16
#define HH 512
#define OO 8
#define NOISE_STD 0.05f
#define ALPHA 0.2f

#define NGROUPS 16   // batch groups
#define BPG 4        // batches per group
#define NSLABS 8     // row slabs per group
#define JS 64        // rows per slab
#define NTHREADS 256

// LDS layout (floats):
//   wrecT4 : 32768  float4[8192]  [k4][j] (j fastest, 64 per k4) -> 128 KB
//   r4     : 2048   float4[512]   [b][k4]                        ->   8 KB
//   wiF    : 1024                 [i][j]                         ->   4 KB
//   zpart  : 1024                 [kq][b][j]                     ->   4 KB
//   xp_lds : 256                  [b][j]                         ->   1 KB
#define SMEM_FLOATS (32768 + 2048 + 1024 + 1024 + 256)
#define SMEM_BYTES (SMEM_FLOATS * 4)

__global__ void __launch_bounds__(NTHREADS, 1) rnn_kernel(
    const float* __restrict__ x, const float* __restrict__ noise,
    const float* __restrict__ wi, const float* __restrict__ si,
    const float* __restrict__ wrec, const float* __restrict__ wo,
    const float* __restrict__ so, const float* __restrict__ h0,
    float* __restrict__ out, float* __restrict__ rbuf0)
{
    extern __shared__ float smem[];
    float4* wrecT4 = (float4*)smem;              // 8192 float4
    float4* r4     = (float4*)(smem + 32768);    // 512 float4
    float*  rflat  = smem + 32768;
    float*  wiF    = smem + 32768 + 2048;
    float*  zpart  = wiF + 1024;
    float*  xp_lds = zpart + 1024;

    const int tid  = threadIdx.x;
    const int grp  = blockIdx.x >> 3;    // 0..15
    const int slab = blockIdx.x & 7;     // 0..7
    const int gb   = grp * BPG;          // first batch of group
    const int j0   = slab * JS;          // first row of slab

    float* rbuf1 = rbuf0 + BB * HH;

    // ---- one-time staging ----
    // wrec slab, transposed to [k4][j] (float4 over k)
    for (int idx = tid; idx < JS * 128; idx += NTHREADS) {
        int j  = idx >> 7;
        int k4 = idx & 127;
        wrecT4[k4 * 64 + j] = ((const float4*)wrec)[(j0 + j) * 128 + k4];
    }
    // wi_full slab: wiF[i][j] = si[i]*wi[i, j0+j]
    for (int idx = tid; idx < II * JS; idx += NTHREADS) {
        int i = idx >> 6;
        int j = idx & 63;
        wiF[idx] = si[i] * wi[i * HH + j0 + j];
    }
    // wo_full in registers for output-computing slabs (slab<4 handles batch gb+slab)
    const int o_out = tid >> 5;   // 0..7
    const int jseg  = tid & 31;   // 0..31
    float wo16[16];
    if (slab < BPG) {
        float sov = so[o_out];
        #pragma unroll
        for (int jj = 0; jj < 16; ++jj)
            wo16[jj] = wo[(jseg + (jj << 5)) * OO + o_out] * sov;
    }
    // r_0 = tanh(h0) broadcast over batches
    for (int idx = tid; idx < 512; idx += NTHREADS) {
        int k4 = idx & 127;
        float4 hv = ((const float4*)h0)[k4];
        float4 rv;
        rv.x = tanhf(hv.x); rv.y = tanhf(hv.y);
        rv.z = tanhf(hv.z); rv.w = tanhf(hv.w);
        r4[idx] = rv;
    }
    // wave-0 owns h for (4 batches) x (its row j0+tid)
    float hreg[BPG];
    if (tid < 64) {
        float hv = h0[j0 + tid];
        #pragma unroll
        for (int b = 0; b < BPG; ++b) hreg[b] = hv;
    }
    __syncthreads();

    cg::grid_group grid = cg::this_grid();

    const int jm = tid & 63;   // row within slab (matvec)
    const int kq = tid >> 6;   // k-quarter / wave id

    for (int t = 0; t < TT; ++t) {
        // wave 0: prefetch noise for this step (consumed after matvec; HBM
        // latency hides under the ~1000-cycle matvec)
        float nz0 = 0.f, nz1 = 0.f, nz2 = 0.f, nz3 = 0.f;
        if (kq == 0) {
            size_t base = ((size_t)gb * TT + t) * HH + j0 + jm;
            nz0 = noise[base];
            nz1 = noise[base + (size_t)TT * HH];
            nz2 = noise[base + 2 * (size_t)TT * HH];
            nz3 = noise[base + 3 * (size_t)TT * HH];
        }
        // wave 1: x-projection for this step into LDS (independent of matvec)
        if (kq == 1) {
            #pragma unroll
            for (int b = 0; b < BPG; ++b) {
                const float4* xb = (const float4*)(x + ((size_t)(gb + b) * TT + t) * II);
                float4 x0 = xb[0], x1 = xb[1], x2 = xb[2], x3 = xb[3];
                float acc = x0.x * wiF[0*64+jm]  + x0.y * wiF[1*64+jm]
                          + x0.z * wiF[2*64+jm]  + x0.w * wiF[3*64+jm]
                          + x1.x * wiF[4*64+jm]  + x1.y * wiF[5*64+jm]
                          + x1.z * wiF[6*64+jm]  + x1.w * wiF[7*64+jm]
                          + x2.x * wiF[8*64+jm]  + x2.y * wiF[9*64+jm]
                          + x2.z * wiF[10*64+jm] + x2.w * wiF[11*64+jm]
                          + x3.x * wiF[12*64+jm] + x3.y * wiF[13*64+jm]
                          + x3.z * wiF[14*64+jm] + x3.w * wiF[15*64+jm];
                xp_lds[b * 64 + jm] = acc;
            }
        }

        // matvec: thread (jm, kq) accumulates z[b, j0+jm] over k in [kq*128, kq*128+128)
        float a0 = 0.f, a1 = 0.f, a2 = 0.f, a3 = 0.f;
        {
            const int kbase = kq << 5;  // float4-chunks
            #pragma unroll 4
            for (int k4 = kbase; k4 < kbase + 32; ++k4) {
                float4 w  = wrecT4[(k4 << 6) + jm];   // lane-consecutive, conflict-free
                float4 ra = r4[k4];                   // uniform per wave -> broadcast
                float4 rb_ = r4[128 + k4];
                float4 rc = r4[256 + k4];
                float4 rd = r4[384 + k4];
                a0 += w.x*ra.x  + w.y*ra.y  + w.z*ra.z  + w.w*ra.w;
                a1 += w.x*rb_.x + w.y*rb_.y + w.z*rb_.z + w.w*rb_.w;
                a2 += w.x*rc.x  + w.y*rc.y  + w.z*rc.z  + w.w*rc.w;
                a3 += w.x*rd.x  + w.y*rd.y  + w.z*rd.z  + w.w*rd.w;
            }
        }
        zpart[(kq*4 + 0)*64 + jm] = a0;
        zpart[(kq*4 + 1)*64 + jm] = a1;
        zpart[(kq*4 + 2)*64 + jm] = a2;
        zpart[(kq*4 + 3)*64 + jm] = a3;
        __syncthreads();

        // wave 0: reduce k-quarters, update h, publish r_{t+1}
        if (tid < 64) {
            int j = tid;
            float* rdst = ((t + 1) & 1) ? rbuf1 : rbuf0;
            float nzv[BPG] = {nz0, nz1, nz2, nz3};
            #pragma unroll
            for (int b = 0; b < BPG; ++b) {
                float z = zpart[(0*4+b)*64+j] + zpart[(1*4+b)*64+j]
                        + zpart[(2*4+b)*64+j] + zpart[(3*4+b)*64+j];
                float h  = hreg[b];
                float hn = h + NOISE_STD * nzv[b] + ALPHA * (z + xp_lds[b*64+j] - h);
                hreg[b] = hn;
                rdst[(size_t)(gb + b) * HH + j0 + j] = tanhf(hn);
            }
        }
        __threadfence();   // release: r slices visible device-wide
        grid.sync();
        __threadfence();   // acquire: L1 refresh so refill sees fresh r

        // refill full r_{t+1} for this group's 4 batches
        {
            const float4* rsrc = (const float4*)((((t + 1) & 1) ? rbuf1 : rbuf0)
                                                 + (size_t)gb * HH);
            r4[tid]       = rsrc[tid];
            r4[tid + 256] = rsrc[tid + 256];
        }
        __syncthreads();

        // out[b, t, :] = r_{t+1}[b,:] @ wo_full  — slab s<4 owns batch gb+s
        if (slab < BPG) {
            const float* rf = rflat + slab * HH;
            float p = 0.f;
            #pragma unroll
            for (int jj = 0; jj < 16; ++jj)
                p += rf[jseg + (jj << 5)] * wo16[jj];
            p += __shfl_xor(p, 1);
            p += __shfl_xor(p, 2);
            p += __shfl_xor(p, 4);
            p += __shfl_xor(p, 8);
            p += __shfl_xor(p, 16);
            if (jseg == 0)
                out[((size_t)(gb + slab) * TT + t) * OO + o_out] = p;
        }
    }
}

extern "C" void kernel_launch(void* const* d_in, const int* in_sizes, int n_in,
                              void* d_out, int out_size, void* d_ws, size_t ws_size,
                              hipStream_t stream) {
    const float* x     = (const float*)d_in[0];
    const float* noise = (const float*)d_in[1];
    const float* wi    = (const float*)d_in[2];
    const float* si    = (const float*)d_in[3];
    const float* wrec  = (const float*)d_in[4];
    const float* wo    = (const float*)d_in[5];
    const float* so    = (const float*)d_in[6];
    const float* h0    = (const float*)d_in[7];
    float* out  = (float*)d_out;
    float* rbuf = (float*)d_ws;   // needs 2*B*H*4 = 256 KB of scratch

    (void)in_sizes; (void)n_in; (void)out_size; (void)ws_size;

    hipFuncSetAttribute((const void*)rnn_kernel,
                        hipFuncAttributeMaxDynamicSharedMemorySize, SMEM_BYTES);

    void* args[] = {(void*)&x, (void*)&noise, (void*)&wi, (void*)&si,
                    (void*)&wrec, (void*)&wo, (void*)&so, (void*)&h0,
                    (void*)&out, (void*)&rbuf};
    hipLaunchCooperativeKernel((void*)rnn_kernel, dim3(NGROUPS * NSLABS), dim3(NTHREADS),
                               args, SMEM_BYTES, stream);
}

// Round 3
// 7504.618 us; speedup vs baseline: 5.1842x; 5.1842x over previous
//
#include <hip/hip_runtime.h>

#define BB 64
#define TT 1000
#define II 16
#define HH 512
#define OO 8
#define NOISE_STD 0.05f
#define ALPHA 0.2f

#define NGROUPS 16   // batch groups (independent sync domains)
#define BPG 4        // batches per group
#define NSLABS 8     // row slabs per group
#define JS 64        // rows per slab
#define NTHREADS 256

// LDS layout (floats):
//   wrecT4 : 32768  float4[8192]  [k4][j] (j fastest, 64 per k4) -> 128 KB
//   r4     : 2048   float4[512]   [b][k4]                        ->   8 KB
//   wiF    : 1024                 [i][j]                         ->   4 KB
//   zpart  : 1024                 [kq][b][j]                     ->   4 KB
//   xp_lds : 256                  [b][j]                         ->   1 KB
#define SMEM_FLOATS (32768 + 2048 + 1024 + 1024 + 256)
#define SMEM_BYTES (SMEM_FLOATS * 4)

#define RBUF_FLOATS (2 * BB * HH)          // double-buffered r, 256 KB
#define FLAG_STRIDE 64                     // uints; one cache line+ per group

__global__ void init_flags(unsigned int* flags) {
    if (threadIdx.x < NGROUPS) flags[threadIdx.x * FLAG_STRIDE] = 0u;
}

__global__ void __launch_bounds__(NTHREADS, 1) rnn_kernel(
    const float* __restrict__ x, const float* __restrict__ noise,
    const float* __restrict__ wi, const float* __restrict__ si,
    const float* __restrict__ wrec, const float* __restrict__ wo,
    const float* __restrict__ so, const float* __restrict__ h0,
    float* __restrict__ out, float* rbuf0, unsigned int* flags)
{
    extern __shared__ float smem[];
    float4* wrecT4 = (float4*)smem;              // 8192 float4
    float4* r4     = (float4*)(smem + 32768);    // 512 float4
    float*  rflat  = smem + 32768;
    float*  wiF    = smem + 32768 + 2048;
    float*  zpart  = wiF + 1024;
    float*  xp_lds = zpart + 1024;

    const int tid  = threadIdx.x;
    // XCD-packing swizzle: block b lands (heuristically) on XCD b%8; give each
    // XCD two complete groups so intra-group traffic stays on one L2/IC port.
    // Correctness does not depend on the mapping (all cross-WG ops are
    // agent-scope coherent).
    const int xcd  = blockIdx.x & 7;
    const int idx  = blockIdx.x >> 3;        // 0..15
    const int grp  = xcd * 2 + (idx >> 3);   // 0..15
    const int slab = idx & 7;                // 0..7
    const int gb   = grp * BPG;              // first batch of group
    const int j0   = slab * JS;              // first row of slab

    float* rbuf1 = rbuf0 + BB * HH;
    unsigned int* bar = flags + grp * FLAG_STRIDE;

    // ---- one-time staging ----
    for (int i2 = tid; i2 < JS * 128; i2 += NTHREADS) {
        int j  = i2 >> 7;
        int k4 = i2 & 127;
        wrecT4[k4 * 64 + j] = ((const float4*)wrec)[(j0 + j) * 128 + k4];
    }
    for (int i2 = tid; i2 < II * JS; i2 += NTHREADS) {
        int i = i2 >> 6;
        int j = i2 & 63;
        wiF[i2] = si[i] * wi[i * HH + j0 + j];
    }
    const int o_out = tid >> 5;   // 0..7
    const int jseg  = tid & 31;   // 0..31
    float wo16[16];
    if (slab < BPG) {
        float sov = so[o_out];
        #pragma unroll
        for (int jj = 0; jj < 16; ++jj)
            wo16[jj] = wo[(jseg + (jj << 5)) * OO + o_out] * sov;
    }
    for (int i2 = tid; i2 < 512; i2 += NTHREADS) {
        int k4 = i2 & 127;
        float4 hv = ((const float4*)h0)[k4];
        float4 rv;
        rv.x = tanhf(hv.x); rv.y = tanhf(hv.y);
        rv.z = tanhf(hv.z); rv.w = tanhf(hv.w);
        r4[i2] = rv;
    }
    float hreg[BPG];
    if (tid < 64) {
        float hv = h0[j0 + tid];
        #pragma unroll
        for (int b = 0; b < BPG; ++b) hreg[b] = hv;
    }
    __syncthreads();

    const int jm = tid & 63;   // row within slab (matvec)
    const int kq = tid >> 6;   // k-quarter / wave id

    for (int t = 0; t < TT; ++t) {
        // wave 0: prefetch noise (registers; consumed in reduce phase)
        float nz0 = 0.f, nz1 = 0.f, nz2 = 0.f, nz3 = 0.f;
        if (kq == 0) {
            size_t base = ((size_t)gb * TT + t) * HH + j0 + jm;
            nz0 = noise[base];
            nz1 = noise[base + (size_t)TT * HH];
            nz2 = noise[base + 2 * (size_t)TT * HH];
            nz3 = noise[base + 3 * (size_t)TT * HH];
        }
        // wave 1: x-projection into LDS
        if (kq == 1) {
            #pragma unroll
            for (int b = 0; b < BPG; ++b) {
                const float4* xb = (const float4*)(x + ((size_t)(gb + b) * TT + t) * II);
                float4 x0 = xb[0], x1 = xb[1], x2 = xb[2], x3 = xb[3];
                float acc = x0.x * wiF[0*64+jm]  + x0.y * wiF[1*64+jm]
                          + x0.z * wiF[2*64+jm]  + x0.w * wiF[3*64+jm]
                          + x1.x * wiF[4*64+jm]  + x1.y * wiF[5*64+jm]
                          + x1.z * wiF[6*64+jm]  + x1.w * wiF[7*64+jm]
                          + x2.x * wiF[8*64+jm]  + x2.y * wiF[9*64+jm]
                          + x2.z * wiF[10*64+jm] + x2.w * wiF[11*64+jm]
                          + x3.x * wiF[12*64+jm] + x3.y * wiF[13*64+jm]
                          + x3.z * wiF[14*64+jm] + x3.w * wiF[15*64+jm];
                xp_lds[b * 64 + jm] = acc;
            }
        }

        // matvec: thread (jm, kq) accumulates z[b, j0+jm] over k-quarter kq
        float a0 = 0.f, a1 = 0.f, a2 = 0.f, a3 = 0.f;
        {
            const int kbase = kq << 5;
            #pragma unroll 4
            for (int k4 = kbase; k4 < kbase + 32; ++k4) {
                float4 w  = wrecT4[(k4 << 6) + jm];
                float4 ra = r4[k4];
                float4 rb_ = r4[128 + k4];
                float4 rc = r4[256 + k4];
                float4 rd = r4[384 + k4];
                a0 += w.x*ra.x  + w.y*ra.y  + w.z*ra.z  + w.w*ra.w;
                a1 += w.x*rb_.x + w.y*rb_.y + w.z*rb_.z + w.w*rb_.w;
                a2 += w.x*rc.x  + w.y*rc.y  + w.z*rc.z  + w.w*rc.w;
                a3 += w.x*rd.x  + w.y*rd.y  + w.z*rd.z  + w.w*rd.w;
            }
        }
        zpart[(kq*4 + 0)*64 + jm] = a0;
        zpart[(kq*4 + 1)*64 + jm] = a1;
        zpart[(kq*4 + 2)*64 + jm] = a2;
        zpart[(kq*4 + 3)*64 + jm] = a3;
        __syncthreads();   // S1

        // wave 0: reduce k-quarters, update h, publish r_{t+1} slice
        if (tid < 64) {
            int j = tid;
            float* rdst = ((t + 1) & 1) ? rbuf1 : rbuf0;
            float nzv[BPG] = {nz0, nz1, nz2, nz3};
            #pragma unroll
            for (int b = 0; b < BPG; ++b) {
                float z = zpart[(0*4+b)*64+j] + zpart[(1*4+b)*64+j]
                        + zpart[(2*4+b)*64+j] + zpart[(3*4+b)*64+j];
                float h  = hreg[b];
                float hn = h + NOISE_STD * nzv[b] + ALPHA * (z + xp_lds[b*64+j] - h);
                hreg[b] = hn;
                // agent-scope relaxed store: write-through to coherent point,
                // no L2 dirty line, no fence needed beyond vmcnt drain
                __hip_atomic_store(&rdst[(size_t)(gb + b) * HH + j0 + j], tanhf(hn),
                                   __ATOMIC_RELAXED, __HIP_MEMORY_SCOPE_AGENT);
            }
        }
        // group barrier: arrive (ordered after the publishes) + spin
        if (tid == 0) {
            asm volatile("s_waitcnt vmcnt(0)" ::: "memory");  // drain sc0sc1 stores
            __hip_atomic_fetch_add(bar, 1u, __ATOMIC_RELAXED, __HIP_MEMORY_SCOPE_AGENT);
            const unsigned int target = 8u * (unsigned int)(t + 1);
            while (__hip_atomic_load(bar, __ATOMIC_RELAXED, __HIP_MEMORY_SCOPE_AGENT) < target) {}
        }
        __syncthreads();   // S2: all waves released once all 8 WGs arrived
        asm volatile("" ::: "memory");

        // refill full r_{t+1} for this group's 4 batches (coherent-point loads,
        // interleaved so each wave's 64 lanes load 512B contiguous per round)
        {
            const unsigned long long* rsrc =
                (const unsigned long long*)((((t + 1) & 1) ? rbuf1 : rbuf0)
                                            + (size_t)gb * HH);
            #pragma unroll
            for (int q = 0; q < 4; ++q) {
                int i2 = q * 256 + tid;   // 0..1023 float2-index
                unsigned long long u = __hip_atomic_load(rsrc + i2,
                                       __ATOMIC_RELAXED, __HIP_MEMORY_SCOPE_AGENT);
                float2 f;
                __builtin_memcpy(&f, &u, 8);
                rflat[i2 * 2 + 0] = f.x;
                rflat[i2 * 2 + 1] = f.y;
            }
        }
        __syncthreads();   // S3

        // out[b, t, :] = r_{t+1}[b,:] @ wo_full — slab s<4 owns batch gb+s
        if (slab < BPG) {
            const float* rf = rflat + slab * HH;
            float p = 0.f;
            #pragma unroll
            for (int jj = 0; jj < 16; ++jj)
                p += rf[jseg + (jj << 5)] * wo16[jj];
            p += __shfl_xor(p, 1);
            p += __shfl_xor(p, 2);
            p += __shfl_xor(p, 4);
            p += __shfl_xor(p, 8);
            p += __shfl_xor(p, 16);
            if (jseg == 0)
                out[((size_t)(gb + slab) * TT + t) * OO + o_out] = p;
        }
    }
}

extern "C" void kernel_launch(void* const* d_in, const int* in_sizes, int n_in,
                              void* d_out, int out_size, void* d_ws, size_t ws_size,
                              hipStream_t stream) {
    const float* x     = (const float*)d_in[0];
    const float* noise = (const float*)d_in[1];
    const float* wi    = (const float*)d_in[2];
    const float* si    = (const float*)d_in[3];
    const float* wrec  = (const float*)d_in[4];
    const float* wo    = (const float*)d_in[5];
    const float* so    = (const float*)d_in[6];
    const float* h0    = (const float*)d_in[7];
    float* out  = (float*)d_out;
    float* rbuf = (float*)d_ws;                          // 256 KB
    unsigned int* flags = (unsigned int*)((float*)d_ws + RBUF_FLOATS);  // +16 KB

    (void)in_sizes; (void)n_in; (void)out_size; (void)ws_size;

    // flags must be zero at the start of EVERY call (graph replays don't
    // re-poison d_ws) — zero them with a plain kernel on the same stream
    init_flags<<<1, 64, 0, stream>>>(flags);

    hipFuncSetAttribute((const void*)rnn_kernel,
                        hipFuncAttributeMaxDynamicSharedMemorySize, SMEM_BYTES);

    void* args[] = {(void*)&x, (void*)&noise, (void*)&wi, (void*)&si,
                    (void*)&wrec, (void*)&wo, (void*)&so, (void*)&h0,
                    (void*)&out, (void*)&rbuf, (void*)&flags};
    hipLaunchCooperativeKernel((void*)rnn_kernel, dim3(NGROUPS * NSLABS), dim3(NTHREADS),
                               args, SMEM_BYTES, stream);
}

// Round 4
// 4149.023 us; speedup vs baseline: 9.3771x; 1.8088x over previous
//
#include <hip/hip_runtime.h>

#define BB 64
#define TT 1000
#define II 16
#define HH 512
#define OO 8
#define NOISE_STD 0.05f
#define ALPHA 0.2f

#define NGROUPS 16   // batch groups (independent sync domains)
#define BPG 4        // batches per group
#define NSLABS 8     // row slabs (WGs) per group
#define JS 64        // rows per slab
#define NTHREADS 512 // 8 waves: wave k8 owns k-slice [k8*64, k8*64+64)

// LDS layout (floats):
//   wrecT4 : 32768  float4[8192] [kk][j] (j fastest)        -> 128 KB
//   rlds   : 4096   [par][b][k]  double-buffered r           ->  16 KB
//   zpart  : 2048   [k8][b][j]                               ->   8 KB
//   xpbuf  : 512    [par][b][j]  x-projection, dbl-buffered  ->   2 KB
#define SMEM_FLOATS (32768 + 4096 + 2048 + 512)
#define SMEM_BYTES (SMEM_FLOATS * 4)   // 157,696 B < 160 KB -> 1 WG/CU

#define FLAG_STRIDE 32                 // 128 B between flags (no false sharing)
#define NFLAGS (NGROUPS * NSLABS)
#define RBUF_FLOATS (2 * BB * HH)      // 256 KB double-buffered r in d_ws

__global__ void init_flags(unsigned int* flags) {
    int i = threadIdx.x;
    if (i < NFLAGS) flags[i * FLAG_STRIDE] = 0u;
}

__global__ void __launch_bounds__(NTHREADS, 1) rnn_kernel(
    const float* __restrict__ x, const float* __restrict__ noise,
    const float* __restrict__ wi, const float* __restrict__ si,
    const float* __restrict__ wrec, const float* __restrict__ wo,
    const float* __restrict__ so, const float* __restrict__ h0,
    float* __restrict__ out, float* rbuf0, unsigned int* flags)
{
    extern __shared__ float smem[];
    float4* wrecT4 = (float4*)smem;                 // [kk*64 + j]
    float*  rlds   = smem + 32768;                  // par*2048 + b*512 + k
    float*  zpart  = smem + 32768 + 4096;           // k8*256 + b*64 + j
    float*  xpbuf  = smem + 32768 + 4096 + 2048;    // par*256 + b*64 + j

    const int tid  = threadIdx.x;
    const int lane = tid & 63;
    const int wid  = tid >> 6;      // matvec: k8; reduce: b (wid<4); out/xp: b=wid-4

    const int xcd  = blockIdx.x & 7;                 // XCD-packing heuristic
    const int bidx = blockIdx.x >> 3;
    const int grp  = xcd * 2 + (bidx >> 3);          // 0..15
    const int slab = bidx & 7;                       // 0..7
    const int gb   = grp * BPG;
    const int j0   = slab * JS;

    float* rbuf1 = rbuf0 + BB * HH;
    unsigned int* gflags = flags + grp * NSLABS * FLAG_STRIDE;

    // ---- one-time staging ----
    for (int i2 = tid; i2 < JS * 128; i2 += NTHREADS) {
        int j  = i2 >> 7;
        int k4 = i2 & 127;
        wrecT4[k4 * 64 + j] = ((const float4*)wrec)[(j0 + j) * 128 + k4];
    }

    float hreg = 0.f;
    if (wid < 4) hreg = h0[j0 + lane];   // h for (batch gb+wid, row j0+lane)

    float wiF_r[16];
    float wo_r[8][8];
    if (wid >= 4) {
        #pragma unroll
        for (int i = 0; i < 16; ++i) wiF_r[i] = si[i] * wi[i * HH + j0 + lane];
        float so_[8];
        #pragma unroll
        for (int o = 0; o < 8; ++o) so_[o] = so[o];
        #pragma unroll
        for (int m = 0; m < 8; ++m) {
            const float4* wrow = (const float4*)(wo + (size_t)(lane + 64 * m) * OO);
            float4 wa = wrow[0], wb2 = wrow[1];
            wo_r[m][0] = wa.x  * so_[0]; wo_r[m][1] = wa.y  * so_[1];
            wo_r[m][2] = wa.z  * so_[2]; wo_r[m][3] = wa.w  * so_[3];
            wo_r[m][4] = wb2.x * so_[4]; wo_r[m][5] = wb2.y * so_[5];
            wo_r[m][6] = wb2.z * so_[6]; wo_r[m][7] = wb2.w * so_[7];
        }
    }

    // r_0 = tanh(h0): every WG stages the full vector locally (no flags at t=0)
    {
        float rv = tanhf(h0[tid]);
        #pragma unroll
        for (int b = 0; b < 4; ++b) rlds[b * 512 + tid] = rv;   // parity 0
    }
    // xp_0
    if (wid >= 4) {
        int b = wid - 4;
        const float4* xb = (const float4*)(x + ((size_t)(gb + b) * TT + 0) * II);
        float4 x0 = xb[0], x1 = xb[1], x2 = xb[2], x3 = xb[3];
        float acc = x0.x*wiF_r[0]  + x0.y*wiF_r[1]  + x0.z*wiF_r[2]  + x0.w*wiF_r[3]
                  + x1.x*wiF_r[4]  + x1.y*wiF_r[5]  + x1.z*wiF_r[6]  + x1.w*wiF_r[7]
                  + x2.x*wiF_r[8]  + x2.y*wiF_r[9]  + x2.z*wiF_r[10] + x2.w*wiF_r[11]
                  + x3.x*wiF_r[12] + x3.y*wiF_r[13] + x3.z*wiF_r[14] + x3.w*wiF_r[15];
        xpbuf[b * 64 + lane] = acc;    // parity 0
    }
    __syncthreads();

    for (int t = 0; t < TT; ++t) {
        const int par = t & 1;
        const int nxt = (t + 1) & 1;

        float nz = 0.f;
        if (wid < 4)   // prefetch; consumed in reduce (hides under matvec)
            nz = noise[((size_t)(gb + wid) * TT + t) * HH + j0 + lane];

        // per-wave rendezvous: wait for producer of slab==wid, load 1KB slice
        if (t > 0 && wid != slab) {
            unsigned int* fl = gflags + wid * FLAG_STRIDE;
            while (__hip_atomic_load(fl, __ATOMIC_RELAXED, __HIP_MEMORY_SCOPE_AGENT)
                   < (unsigned int)t) {}
            const float* rsrc = par ? rbuf1 : rbuf0;
            const int k = wid * 64 + lane;
            #pragma unroll
            for (int b = 0; b < 4; ++b) {
                float v = __hip_atomic_load(&rsrc[(size_t)(gb + b) * HH + k],
                                            __ATOMIC_RELAXED, __HIP_MEMORY_SCOPE_AGENT);
                rlds[par * 2048 + b * 512 + k] = v;
            }
        }
        // (wid==slab slice was short-circuited into rlds by reduce of t-1 / init)

        // matvec: wave k8=wid accumulates z-partials over its own 64-k slice
        float a0 = 0.f, a1 = 0.f, a2 = 0.f, a3 = 0.f;
        {
            const float4* rl4 = (const float4*)(rlds + par * 2048);
            const int kk0 = wid * 16;
            #pragma unroll
            for (int k4 = 0; k4 < 16; ++k4) {
                const int kk = kk0 + k4;
                float4 w  = wrecT4[kk * 64 + lane];   // lane-consecutive b128
                float4 r0 = rl4[0 * 128 + kk];        // wave-uniform broadcasts
                float4 r1 = rl4[1 * 128 + kk];
                float4 r2 = rl4[2 * 128 + kk];
                float4 r3 = rl4[3 * 128 + kk];
                a0 += w.x*r0.x + w.y*r0.y + w.z*r0.z + w.w*r0.w;
                a1 += w.x*r1.x + w.y*r1.y + w.z*r1.z + w.w*r1.w;
                a2 += w.x*r2.x + w.y*r2.y + w.z*r2.z + w.w*r2.w;
                a3 += w.x*r3.x + w.y*r3.y + w.z*r3.z + w.w*r3.w;
            }
        }
        zpart[wid * 256 + 0 * 64 + lane] = a0;
        zpart[wid * 256 + 1 * 64 + lane] = a1;
        zpart[wid * 256 + 2 * 64 + lane] = a2;
        zpart[wid * 256 + 3 * 64 + lane] = a3;
        __syncthreads();   // S1: zpart complete, rlds[par] (= r_t) complete

        if (wid < 4) {
            // reduce 8 k-slices + h-update + publish r_{t+1}  (b=wid, j=lane)
            float z = 0.f;
            #pragma unroll
            for (int k8 = 0; k8 < 8; ++k8)
                z += zpart[k8 * 256 + wid * 64 + lane];
            float xp = xpbuf[par * 256 + wid * 64 + lane];
            float hn = hreg + NOISE_STD * nz + ALPHA * (z + xp - hreg);
            hreg = hn;
            float rnew = tanhf(hn);
            float* rdst = nxt ? rbuf1 : rbuf0;
            __hip_atomic_store(&rdst[(size_t)(gb + wid) * HH + j0 + lane], rnew,
                               __ATOMIC_RELAXED, __HIP_MEMORY_SCOPE_AGENT);
            rlds[nxt * 2048 + wid * 512 + j0 + lane] = rnew;  // own-slab shortcut
        } else {
            const int b = wid - 4;
            // out_{t-1} = r_t @ wo_full — fully inside the S1->S2 shadow
            if (t > 0) {
                float acc0=0.f,acc1=0.f,acc2=0.f,acc3=0.f,
                      acc4=0.f,acc5=0.f,acc6=0.f,acc7=0.f;
                #pragma unroll
                for (int m = 0; m < 8; ++m) {
                    float rv = rlds[par * 2048 + b * 512 + lane + 64 * m];
                    acc0 += rv * wo_r[m][0]; acc1 += rv * wo_r[m][1];
                    acc2 += rv * wo_r[m][2]; acc3 += rv * wo_r[m][3];
                    acc4 += rv * wo_r[m][4]; acc5 += rv * wo_r[m][5];
                    acc6 += rv * wo_r[m][6]; acc7 += rv * wo_r[m][7];
                }
                float res = 0.f;
                #define RED_(A, O) { float v_ = A; \
                    v_ += __shfl_xor(v_, 1);  v_ += __shfl_xor(v_, 2); \
                    v_ += __shfl_xor(v_, 4);  v_ += __shfl_xor(v_, 8); \
                    v_ += __shfl_xor(v_, 16); v_ += __shfl_xor(v_, 32); \
                    if (lane == O) res = v_; }
                RED_(acc0, 0) RED_(acc1, 1) RED_(acc2, 2) RED_(acc3, 3)
                RED_(acc4, 4) RED_(acc5, 5) RED_(acc6, 6) RED_(acc7, 7)
                #undef RED_
                if (lane < 8)
                    out[((size_t)(gb + b) * TT + (t - 1)) * OO + lane] = res;
            }
            // x-projection for step t+1 (off critical path)
            if (t + 1 < TT) {
                const float4* xb =
                    (const float4*)(x + ((size_t)(gb + b) * TT + (t + 1)) * II);
                float4 x0 = xb[0], x1 = xb[1], x2 = xb[2], x3 = xb[3];
                float acc = x0.x*wiF_r[0]  + x0.y*wiF_r[1]  + x0.z*wiF_r[2]  + x0.w*wiF_r[3]
                          + x1.x*wiF_r[4]  + x1.y*wiF_r[5]  + x1.z*wiF_r[6]  + x1.w*wiF_r[7]
                          + x2.x*wiF_r[8]  + x2.y*wiF_r[9]  + x2.z*wiF_r[10] + x2.w*wiF_r[11]
                          + x3.x*wiF_r[12] + x3.y*wiF_r[13] + x3.z*wiF_r[14] + x3.w*wiF_r[15];
                xpbuf[nxt * 256 + b * 64 + lane] = acc;
            }
        }
        asm volatile("s_waitcnt vmcnt(0)" ::: "memory");  // drain publishes
        __syncthreads();   // S2
        if (tid == 0)      // single writer per flag; publishes drained by S2
            __hip_atomic_store(gflags + slab * FLAG_STRIDE, (unsigned int)(t + 1),
                               __ATOMIC_RELAXED, __HIP_MEMORY_SCOPE_AGENT);
    }

    // epilogue: stage r_T (parity 0) and emit out_{T-1}
    if (wid != slab) {
        unsigned int* fl = gflags + wid * FLAG_STRIDE;
        while (__hip_atomic_load(fl, __ATOMIC_RELAXED, __HIP_MEMORY_SCOPE_AGENT)
               < (unsigned int)TT) {}
        const int k = wid * 64 + lane;
        #pragma unroll
        for (int b = 0; b < 4; ++b) {
            float v = __hip_atomic_load(&rbuf0[(size_t)(gb + b) * HH + k],
                                        __ATOMIC_RELAXED, __HIP_MEMORY_SCOPE_AGENT);
            rlds[b * 512 + k] = v;
        }
    }
    __syncthreads();
    if (wid >= 4) {
        const int b = wid - 4;
        float acc0=0.f,acc1=0.f,acc2=0.f,acc3=0.f,acc4=0.f,acc5=0.f,acc6=0.f,acc7=0.f;
        #pragma unroll
        for (int m = 0; m < 8; ++m) {
            float rv = rlds[b * 512 + lane + 64 * m];
            acc0 += rv * wo_r[m][0]; acc1 += rv * wo_r[m][1];
            acc2 += rv * wo_r[m][2]; acc3 += rv * wo_r[m][3];
            acc4 += rv * wo_r[m][4]; acc5 += rv * wo_r[m][5];
            acc6 += rv * wo_r[m][6]; acc7 += rv * wo_r[m][7];
        }
        float res = 0.f;
        #define RED_(A, O) { float v_ = A; \
            v_ += __shfl_xor(v_, 1);  v_ += __shfl_xor(v_, 2); \
            v_ += __shfl_xor(v_, 4);  v_ += __shfl_xor(v_, 8); \
            v_ += __shfl_xor(v_, 16); v_ += __shfl_xor(v_, 32); \
            if (lane == O) res = v_; }
        RED_(acc0, 0) RED_(acc1, 1) RED_(acc2, 2) RED_(acc3, 3)
        RED_(acc4, 4) RED_(acc5, 5) RED_(acc6, 6) RED_(acc7, 7)
        #undef RED_
        if (lane < 8)
            out[((size_t)(gb + b) * TT + (TT - 1)) * OO + lane] = res;
    }
}

extern "C" void kernel_launch(void* const* d_in, const int* in_sizes, int n_in,
                              void* d_out, int out_size, void* d_ws, size_t ws_size,
                              hipStream_t stream) {
    const float* x     = (const float*)d_in[0];
    const float* noise = (const float*)d_in[1];
    const float* wi    = (const float*)d_in[2];
    const float* si    = (const float*)d_in[3];
    const float* wrec  = (const float*)d_in[4];
    const float* wo    = (const float*)d_in[5];
    const float* so    = (const float*)d_in[6];
    const float* h0    = (const float*)d_in[7];
    float* out  = (float*)d_out;
    float* rbuf = (float*)d_ws;                                        // 256 KB
    unsigned int* flags = (unsigned int*)((float*)d_ws + RBUF_FLOATS); // +16 KB

    (void)in_sizes; (void)n_in; (void)out_size; (void)ws_size;

    // flags must be zero at the start of EVERY call (graph replays don't
    // re-poison d_ws)
    init_flags<<<1, 128, 0, stream>>>(flags);

    hipFuncSetAttribute((const void*)rnn_kernel,
                        hipFuncAttributeMaxDynamicSharedMemorySize, SMEM_BYTES);

    void* args[] = {(void*)&x, (void*)&noise, (void*)&wi, (void*)&si,
                    (void*)&wrec, (void*)&wo, (void*)&so, (void*)&h0,
                    (void*)&out, (void*)&rbuf, (void*)&flags};
    hipLaunchCooperativeKernel((void*)rnn_kernel, dim3(NGROUPS * NSLABS),
                               dim3(NTHREADS), args, SMEM_BYTES, stream);
}

// Round 5
// 2082.732 us; speedup vs baseline: 18.6802x; 1.9921x over previous
//
#include <hip/hip_runtime.h>

#define BB 64
#define TT 1000
#define II 16
#define HH 512
#define OO 8
#define NOISE_STD 0.05f
#define ALPHA 0.2f

#define NGROUPS 32   // batch groups (independent sync domains)
#define BPG 2        // batches per group
#define NSLABS 8     // row slabs (WGs) per group
#define JS 64        // rows per slab
#define NTHREADS 512 // 8 waves; wave w owns k-slice [w*64, w*64+64)
#define NBLOCKS (NGROUPS * NSLABS)   // 256 = one WG per CU

// d_ws: rtag[2][BB][HH] uint64 — (tag<<32 | r_bits), parity-double-buffered.
// Equality-tag protocol => no init kernel needed (stale/poison tags never
// equal the awaited tag; see publish-requires-prior-consumption chain).

__global__ void __launch_bounds__(NTHREADS, 1) rnn_kernel(
    const float* __restrict__ x, const float* __restrict__ noise,
    const float* __restrict__ wi, const float* __restrict__ si,
    const float* __restrict__ wrec, const float* __restrict__ wo,
    const float* __restrict__ so, const float* __restrict__ h0,
    float* __restrict__ out, unsigned long long* rtag)
{
    __shared__ __align__(16) float rlds[2][BPG][HH];        // [par][b][k]  4 KB
    __shared__ __align__(16) float zpart[NSLABS][BPG][JS];  //              4 KB
    __shared__ __align__(16) float xpbuf[2][BPG][JS];       //              1 KB

    const int tid  = threadIdx.x;
    const int lane = tid & 63;
    const int wid  = tid >> 6;

    const int xcd  = blockIdx.x & 7;          // XCD-packing heuristic only
    const int bidx = blockIdx.x >> 3;         // 0..31
    const int grp  = xcd * 4 + (bidx >> 3);   // 0..31
    const int slab = bidx & 7;                // 0..7
    const int gb   = grp * BPG;
    const int j0   = slab * JS;

    // ---- one-time staging ----
    // wrec row (j0+lane), k-slice [wid*64, +64) -> 64 registers
    float w_reg[64];
    {
        const float4* wrow = (const float4*)(wrec + (size_t)(j0 + lane) * HH + wid * 64);
        #pragma unroll
        for (int c = 0; c < 16; ++c) {
            float4 v = wrow[c];
            w_reg[4*c+0] = v.x; w_reg[4*c+1] = v.y;
            w_reg[4*c+2] = v.z; w_reg[4*c+3] = v.w;
        }
    }

    float hreg = 0.f;
    if (wid < BPG) hreg = h0[j0 + lane];      // h for (batch gb+wid, row j0+lane)

    float wiF_r[16];                           // waves 6,7: x-projection weights
    if (wid >= 6) {
        #pragma unroll
        for (int i = 0; i < 16; ++i) wiF_r[i] = si[i] * wi[i * HH + j0 + lane];
    }
    float wo_r[8][8];                          // waves 4,5: output weights
    if (wid == 4 || wid == 5) {
        float so_[8];
        #pragma unroll
        for (int o = 0; o < 8; ++o) so_[o] = so[o];
        #pragma unroll
        for (int m = 0; m < 8; ++m) {
            const float4* wrow = (const float4*)(wo + (size_t)(lane + 64 * m) * OO);
            float4 wa = wrow[0], wb2 = wrow[1];
            wo_r[m][0] = wa.x  * so_[0]; wo_r[m][1] = wa.y  * so_[1];
            wo_r[m][2] = wa.z  * so_[2]; wo_r[m][3] = wa.w  * so_[3];
            wo_r[m][4] = wb2.x * so_[4]; wo_r[m][5] = wb2.y * so_[5];
            wo_r[m][6] = wb2.z * so_[6]; wo_r[m][7] = wb2.w * so_[7];
        }
    }

    // r_0 = tanh(h0) staged locally by every WG (no poll at t=0)
    {
        float rv = tanhf(h0[tid]);
        rlds[0][0][tid] = rv;
        rlds[0][1][tid] = rv;
    }
    // xp_0
    if (wid >= 6) {
        const int b = wid - 6;
        const float4* xb = (const float4*)(x + ((size_t)(gb + b) * TT + 0) * II);
        float4 x0 = xb[0], x1 = xb[1], x2 = xb[2], x3 = xb[3];
        xpbuf[0][b][lane] =
              x0.x*wiF_r[0]  + x0.y*wiF_r[1]  + x0.z*wiF_r[2]  + x0.w*wiF_r[3]
            + x1.x*wiF_r[4]  + x1.y*wiF_r[5]  + x1.z*wiF_r[6]  + x1.w*wiF_r[7]
            + x2.x*wiF_r[8]  + x2.y*wiF_r[9]  + x2.z*wiF_r[10] + x2.w*wiF_r[11]
            + x3.x*wiF_r[12] + x3.y*wiF_r[13] + x3.z*wiF_r[14] + x3.w*wiF_r[15];
    }
    __syncthreads();

    for (int t = 0; t < TT; ++t) {
        const int par = t & 1;
        const int nxt = (t + 1) & 1;

        float nz = 0.f;
        if (wid < BPG)   // prefetch; consumed after S1 (hides under poll+matvec)
            nz = noise[((size_t)(gb + wid) * TT + t) * HH + j0 + lane];

        // per-wave rendezvous: poll OWN slice, tag == t (single IC round trip)
        if (t > 0 && wid != slab) {
            const unsigned long long* s0 =
                rtag + (size_t)par * (BB * HH) + (size_t)gb * HH + wid * 64 + lane;
            unsigned long long v0, v1;
            const unsigned int tg = (unsigned int)t;
            do {
                v0 = __hip_atomic_load(s0,      __ATOMIC_RELAXED, __HIP_MEMORY_SCOPE_AGENT);
                v1 = __hip_atomic_load(s0 + HH, __ATOMIC_RELAXED, __HIP_MEMORY_SCOPE_AGENT);
            } while ((unsigned int)(v0 >> 32) != tg || (unsigned int)(v1 >> 32) != tg);
            rlds[par][0][wid * 64 + lane] = __uint_as_float((unsigned int)v0);
            rlds[par][1][wid * 64 + lane] = __uint_as_float((unsigned int)v1);
        }
        // (wid==slab slice was written by reduce waves last iter; guarded by S2)

        // matvec on own slice: w in regs, r via wave-uniform b128 broadcasts
        float a0 = 0.f, a1 = 0.f;
        {
            const float4* r0p = (const float4*)&rlds[par][0][wid * 64];
            const float4* r1p = (const float4*)&rlds[par][1][wid * 64];
            #pragma unroll
            for (int c = 0; c < 16; ++c) {
                float4 r0 = r0p[c];
                float4 r1 = r1p[c];
                a0 += w_reg[4*c+0]*r0.x + w_reg[4*c+1]*r0.y
                    + w_reg[4*c+2]*r0.z + w_reg[4*c+3]*r0.w;
                a1 += w_reg[4*c+0]*r1.x + w_reg[4*c+1]*r1.y
                    + w_reg[4*c+2]*r1.z + w_reg[4*c+3]*r1.w;
            }
        }
        zpart[wid][0][lane] = a0;
        zpart[wid][1][lane] = a1;
        __syncthreads();   // S1: zpart + rlds[par] complete

        if (wid < BPG) {
            // reduce 8 k-slices + h-update + tagged publish (b=wid, j=lane)
            float z = 0.f;
            #pragma unroll
            for (int k8 = 0; k8 < 8; ++k8) z += zpart[k8][wid][lane];
            float xp = xpbuf[par][wid][lane];
            float hn = hreg + NOISE_STD * nz + ALPHA * (z + xp - hreg);
            hreg = hn;
            float rnew = tanhf(hn);
            unsigned long long pv =
                ((unsigned long long)(unsigned int)(t + 1) << 32)
              | (unsigned long long)__float_as_uint(rnew);
            __hip_atomic_store(rtag + (size_t)nxt * (BB * HH)
                                    + (size_t)(gb + wid) * HH + j0 + lane,
                               pv, __ATOMIC_RELAXED, __HIP_MEMORY_SCOPE_AGENT);
            rlds[nxt][wid][j0 + lane] = rnew;   // own-slab shortcut
        } else if (wid == 4 || wid == 5) {
            // out[t-1] = r_t @ wo_full — in the S1->S2 shadow
            const int b = wid - 4;
            if (t > 0) {
                float acc0=0.f,acc1=0.f,acc2=0.f,acc3=0.f,
                      acc4=0.f,acc5=0.f,acc6=0.f,acc7=0.f;
                #pragma unroll
                for (int m = 0; m < 8; ++m) {
                    float rv = rlds[par][b][lane + 64 * m];
                    acc0 += rv * wo_r[m][0]; acc1 += rv * wo_r[m][1];
                    acc2 += rv * wo_r[m][2]; acc3 += rv * wo_r[m][3];
                    acc4 += rv * wo_r[m][4]; acc5 += rv * wo_r[m][5];
                    acc6 += rv * wo_r[m][6]; acc7 += rv * wo_r[m][7];
                }
                float res = 0.f;
                #define RED_(A, O) { float v_ = A; \
                    v_ += __shfl_xor(v_, 1);  v_ += __shfl_xor(v_, 2); \
                    v_ += __shfl_xor(v_, 4);  v_ += __shfl_xor(v_, 8); \
                    v_ += __shfl_xor(v_, 16); v_ += __shfl_xor(v_, 32); \
                    if (lane == O) res = v_; }
                RED_(acc0, 0) RED_(acc1, 1) RED_(acc2, 2) RED_(acc3, 3)
                RED_(acc4, 4) RED_(acc5, 5) RED_(acc6, 6) RED_(acc7, 7)
                #undef RED_
                if (lane < 8)
                    out[((size_t)(gb + b) * TT + (t - 1)) * OO + lane] = res;
            }
        } else if (wid >= 6) {
            // x-projection for step t+1 (off critical path)
            const int b = wid - 6;
            if (t + 1 < TT) {
                const float4* xb =
                    (const float4*)(x + ((size_t)(gb + b) * TT + (t + 1)) * II);
                float4 x0 = xb[0], x1 = xb[1], x2 = xb[2], x3 = xb[3];
                xpbuf[nxt][b][lane] =
                      x0.x*wiF_r[0]  + x0.y*wiF_r[1]  + x0.z*wiF_r[2]  + x0.w*wiF_r[3]
                    + x1.x*wiF_r[4]  + x1.y*wiF_r[5]  + x1.z*wiF_r[6]  + x1.w*wiF_r[7]
                    + x2.x*wiF_r[8]  + x2.y*wiF_r[9]  + x2.z*wiF_r[10] + x2.w*wiF_r[11]
                    + x3.x*wiF_r[12] + x3.y*wiF_r[13] + x3.z*wiF_r[14] + x3.w*wiF_r[15];
            }
        }
        __syncthreads();   // S2: rlds[nxt] shortcut + xpbuf[nxt] published intra-WG
    }

    // epilogue: stage r_TT (parity 0, tag TT) and emit out[TT-1]
    if (wid != slab) {
        const unsigned long long* s0 =
            rtag + (size_t)gb * HH + wid * 64 + lane;   // parity 0
        unsigned long long v0, v1;
        const unsigned int tg = (unsigned int)TT;
        do {
            v0 = __hip_atomic_load(s0,      __ATOMIC_RELAXED, __HIP_MEMORY_SCOPE_AGENT);
            v1 = __hip_atomic_load(s0 + HH, __ATOMIC_RELAXED, __HIP_MEMORY_SCOPE_AGENT);
        } while ((unsigned int)(v0 >> 32) != tg || (unsigned int)(v1 >> 32) != tg);
        rlds[0][0][wid * 64 + lane] = __uint_as_float((unsigned int)v0);
        rlds[0][1][wid * 64 + lane] = __uint_as_float((unsigned int)v1);
    }
    __syncthreads();
    if (wid == 4 || wid == 5) {
        const int b = wid - 4;
        float acc0=0.f,acc1=0.f,acc2=0.f,acc3=0.f,acc4=0.f,acc5=0.f,acc6=0.f,acc7=0.f;
        #pragma unroll
        for (int m = 0; m < 8; ++m) {
            float rv = rlds[0][b][lane + 64 * m];
            acc0 += rv * wo_r[m][0]; acc1 += rv * wo_r[m][1];
            acc2 += rv * wo_r[m][2]; acc3 += rv * wo_r[m][3];
            acc4 += rv * wo_r[m][4]; acc5 += rv * wo_r[m][5];
            acc6 += rv * wo_r[m][6]; acc7 += rv * wo_r[m][7];
        }
        float res = 0.f;
        #define RED_(A, O) { float v_ = A; \
            v_ += __shfl_xor(v_, 1);  v_ += __shfl_xor(v_, 2); \
            v_ += __shfl_xor(v_, 4);  v_ += __shfl_xor(v_, 8); \
            v_ += __shfl_xor(v_, 16); v_ += __shfl_xor(v_, 32); \
            if (lane == O) res = v_; }
        RED_(acc0, 0) RED_(acc1, 1) RED_(acc2, 2) RED_(acc3, 3)
        RED_(acc4, 4) RED_(acc5, 5) RED_(acc6, 6) RED_(acc7, 7)
        #undef RED_
        if (lane < 8)
            out[((size_t)(gb + b) * TT + (TT - 1)) * OO + lane] = res;
    }
}

extern "C" void kernel_launch(void* const* d_in, const int* in_sizes, int n_in,
                              void* d_out, int out_size, void* d_ws, size_t ws_size,
                              hipStream_t stream) {
    const float* x     = (const float*)d_in[0];
    const float* noise = (const float*)d_in[1];
    const float* wi    = (const float*)d_in[2];
    const float* si    = (const float*)d_in[3];
    const float* wrec  = (const float*)d_in[4];
    const float* wo    = (const float*)d_in[5];
    const float* so    = (const float*)d_in[6];
    const float* h0    = (const float*)d_in[7];
    float* out = (float*)d_out;
    unsigned long long* rtag = (unsigned long long*)d_ws;   // 512 KB

    (void)in_sizes; (void)n_in; (void)out_size; (void)ws_size;

    void* args[] = {(void*)&x, (void*)&noise, (void*)&wi, (void*)&si,
                    (void*)&wrec, (void*)&wo, (void*)&so, (void*)&h0,
                    (void*)&out, (void*)&rtag};
    hipLaunchCooperativeKernel((void*)rnn_kernel, dim3(NBLOCKS), dim3(NTHREADS),
                               args, 0, stream);
}

// Round 6
// 1991.847 us; speedup vs baseline: 19.5325x; 1.0456x over previous
//
#include <hip/hip_runtime.h>

#define BB 64
#define TT 1000
#define II 16
#define HH 512
#define OO 8
#define NOISE_STD 0.05f
#define ALPHA 0.2f

#define NGROUPS 32   // batch groups (independent sync domains)
#define BPG 2        // batches per group
#define NSLABS 8     // row slabs (WGs) per group
#define JS 64        // rows per slab
#define NTHREADS 512 // 8 waves; wave w owns k-slice [w*64, w*64+64)
#define NBLOCKS (NGROUPS * NSLABS)   // 256 = one WG per CU

// d_ws: rtag[2][BB][HH] uint64 — (tag<<32 | r_bits), parity-double-buffered.
// Equality-tag protocol: a slot awaiting tag t can only contain {stale != t, t}
// (each slot is overwritten with tags t-2, t-4, ... before the await of t, and
// consumption of t-2 happens-before the await of t). 0xAA poison never matches.

__global__ void __launch_bounds__(NTHREADS, 1) rnn_kernel(
    const float* __restrict__ x, const float* __restrict__ noise,
    const float* __restrict__ wi, const float* __restrict__ si,
    const float* __restrict__ wrec, const float* __restrict__ wo,
    const float* __restrict__ so, const float* __restrict__ h0,
    float* __restrict__ out, unsigned long long* rtag)
{
    __shared__ __align__(16) float rlds[2][BPG][HH];          // for out-waves  8 KB
    __shared__ __align__(16) float zpart[2][NSLABS][BPG][JS]; // parity-dbuf    8 KB
    __shared__ __align__(16) float xpbuf[2][BPG][JS];         //                1 KB

    const int tid  = threadIdx.x;
    const int lane = tid & 63;
    const int wid  = tid >> 6;

    const int xcd  = blockIdx.x & 7;          // XCD-packing heuristic only
    const int bidx = blockIdx.x >> 3;         // 0..31
    const int grp  = xcd * 4 + (bidx >> 3);   // 0..31
    const int slab = bidx & 7;                // 0..7
    const int gb   = grp * BPG;
    const int j0   = slab * JS;

    // ---- one-time staging ----
    // wrec row (j0+lane), k-slice [wid*64, +64) -> 64 registers
    float w_reg[64];
    {
        const float4* wrow = (const float4*)(wrec + (size_t)(j0 + lane) * HH + wid * 64);
        #pragma unroll
        for (int c = 0; c < 16; ++c) {
            float4 v = wrow[c];
            w_reg[4*c+0] = v.x; w_reg[4*c+1] = v.y;
            w_reg[4*c+2] = v.z; w_reg[4*c+3] = v.w;
        }
    }

    float hreg = 0.f;
    if (wid < BPG) hreg = h0[j0 + lane];      // h for (batch gb+wid, row j0+lane)

    float wiF_r[16];                           // waves 6,7: x-projection weights
    if (wid >= 6) {
        #pragma unroll
        for (int i = 0; i < 16; ++i) wiF_r[i] = si[i] * wi[i * HH + j0 + lane];
    }
    float wo_r[8][8];                          // waves 4,5: output weights
    if (wid == 4 || wid == 5) {
        float so_[8];
        #pragma unroll
        for (int o = 0; o < 8; ++o) so_[o] = so[o];
        #pragma unroll
        for (int m = 0; m < 8; ++m) {
            const float4* wrow = (const float4*)(wo + (size_t)(lane + 64 * m) * OO);
            float4 wa = wrow[0], wb2 = wrow[1];
            wo_r[m][0] = wa.x  * so_[0]; wo_r[m][1] = wa.y  * so_[1];
            wo_r[m][2] = wa.z  * so_[2]; wo_r[m][3] = wa.w  * so_[3];
            wo_r[m][4] = wb2.x * so_[4]; wo_r[m][5] = wb2.y * so_[5];
            wo_r[m][6] = wb2.z * so_[6]; wo_r[m][7] = wb2.w * so_[7];
        }
    }

    // r_0 = tanh(h0): wave w's slice in registers + staged for out waves
    unsigned int rb0, rb1;
    {
        float rv = tanhf(h0[wid * 64 + lane]);
        rb0 = __float_as_uint(rv);
        rb1 = rb0;
        rlds[0][0][wid * 64 + lane] = rv;
        rlds[0][1][wid * 64 + lane] = rv;
    }
    // xp_0
    if (wid >= 6) {
        const int b = wid - 6;
        const float4* xb = (const float4*)(x + ((size_t)(gb + b) * TT + 0) * II);
        float4 x0 = xb[0], x1 = xb[1], x2 = xb[2], x3 = xb[3];
        xpbuf[0][b][lane] =
              x0.x*wiF_r[0]  + x0.y*wiF_r[1]  + x0.z*wiF_r[2]  + x0.w*wiF_r[3]
            + x1.x*wiF_r[4]  + x1.y*wiF_r[5]  + x1.z*wiF_r[6]  + x1.w*wiF_r[7]
            + x2.x*wiF_r[8]  + x2.y*wiF_r[9]  + x2.z*wiF_r[10] + x2.w*wiF_r[11]
            + x3.x*wiF_r[12] + x3.y*wiF_r[13] + x3.z*wiF_r[14] + x3.w*wiF_r[15];
    }
    __syncthreads();

    for (int t = 0; t < TT; ++t) {
        const int par = t & 1;
        const int nxt = (t + 1) & 1;

        float nz = 0.f;
        if (wid < BPG)   // prefetch; consumed after S1 (hides under poll+matvec)
            nz = noise[((size_t)(gb + wid) * TT + t) * HH + j0 + lane];

        // per-wave rendezvous: poll OWN slice (tag == t), keep r in VGPRs
        if (t > 0) {
            const unsigned long long* s0 =
                rtag + (size_t)par * (BB * HH) + (size_t)gb * HH + wid * 64 + lane;
            unsigned long long v0, v1;
            const unsigned int tg = (unsigned int)t;
            do {
                v0 = __hip_atomic_load(s0,      __ATOMIC_RELAXED, __HIP_MEMORY_SCOPE_AGENT);
                v1 = __hip_atomic_load(s0 + HH, __ATOMIC_RELAXED, __HIP_MEMORY_SCOPE_AGENT);
            } while ((unsigned int)(v0 >> 32) != tg || (unsigned int)(v1 >> 32) != tg);
            rb0 = (unsigned int)v0;
            rb1 = (unsigned int)v1;
            // stage for the out-waves' wo-matvec (per-lane b32, conflict-free)
            rlds[par][0][wid * 64 + lane] = __uint_as_float(rb0);
            rlds[par][1][wid * 64 + lane] = __uint_as_float(rb1);
        }

        // matvec on own slice: w in regs, r broadcast via v_readlane (VALU pipe,
        // zero LDS traffic)
        float a0 = 0.f, a1 = 0.f;
        #pragma unroll
        for (int c = 0; c < 64; ++c) {
            float r0 = __uint_as_float(__builtin_amdgcn_readlane(rb0, c));
            float r1 = __uint_as_float(__builtin_amdgcn_readlane(rb1, c));
            a0 += w_reg[c] * r0;
            a1 += w_reg[c] * r1;
        }
        zpart[par][wid][0][lane] = a0;
        zpart[par][wid][1][lane] = a1;
        __syncthreads();   // S1 (the only barrier): zpart[par] + rlds[par] ready

        if (wid < BPG) {
            // reduce 8 k-slices + h-update + tagged publish (b=wid, j=lane)
            float z = 0.f;
            #pragma unroll
            for (int k8 = 0; k8 < 8; ++k8) z += zpart[par][k8][wid][lane];
            float xp = xpbuf[par][wid][lane];
            float hn = hreg + NOISE_STD * nz + ALPHA * (z + xp - hreg);
            hreg = hn;
            float rnew = tanhf(hn);
            unsigned long long pv =
                ((unsigned long long)(unsigned int)(t + 1) << 32)
              | (unsigned long long)__float_as_uint(rnew);
            __hip_atomic_store(rtag + (size_t)nxt * (BB * HH)
                                    + (size_t)(gb + wid) * HH + j0 + lane,
                               pv, __ATOMIC_RELAXED, __HIP_MEMORY_SCOPE_AGENT);
        } else if (wid == 4 || wid == 5) {
            // out[t-1] = r_t @ wo_full — off the critical path
            const int b = wid - 4;
            if (t > 0) {
                float acc0=0.f,acc1=0.f,acc2=0.f,acc3=0.f,
                      acc4=0.f,acc5=0.f,acc6=0.f,acc7=0.f;
                #pragma unroll
                for (int m = 0; m < 8; ++m) {
                    float rv = rlds[par][b][lane + 64 * m];
                    acc0 += rv * wo_r[m][0]; acc1 += rv * wo_r[m][1];
                    acc2 += rv * wo_r[m][2]; acc3 += rv * wo_r[m][3];
                    acc4 += rv * wo_r[m][4]; acc5 += rv * wo_r[m][5];
                    acc6 += rv * wo_r[m][6]; acc7 += rv * wo_r[m][7];
                }
                float res = 0.f;
                #define RED_(A, O) { float v_ = A; \
                    v_ += __shfl_xor(v_, 1);  v_ += __shfl_xor(v_, 2); \
                    v_ += __shfl_xor(v_, 4);  v_ += __shfl_xor(v_, 8); \
                    v_ += __shfl_xor(v_, 16); v_ += __shfl_xor(v_, 32); \
                    if (lane == O) res = v_; }
                RED_(acc0, 0) RED_(acc1, 1) RED_(acc2, 2) RED_(acc3, 3)
                RED_(acc4, 4) RED_(acc5, 5) RED_(acc6, 6) RED_(acc7, 7)
                #undef RED_
                if (lane < 8)
                    out[((size_t)(gb + b) * TT + (t - 1)) * OO + lane] = res;
            }
        } else if (wid >= 6) {
            // x-projection for step t+1 (off critical path)
            const int b = wid - 6;
            if (t + 1 < TT) {
                const float4* xb =
                    (const float4*)(x + ((size_t)(gb + b) * TT + (t + 1)) * II);
                float4 x0 = xb[0], x1 = xb[1], x2 = xb[2], x3 = xb[3];
                xpbuf[nxt][b][lane] =
                      x0.x*wiF_r[0]  + x0.y*wiF_r[1]  + x0.z*wiF_r[2]  + x0.w*wiF_r[3]
                    + x1.x*wiF_r[4]  + x1.y*wiF_r[5]  + x1.z*wiF_r[6]  + x1.w*wiF_r[7]
                    + x2.x*wiF_r[8]  + x2.y*wiF_r[9]  + x2.z*wiF_r[10] + x2.w*wiF_r[11]
                    + x3.x*wiF_r[12] + x3.y*wiF_r[13] + x3.z*wiF_r[14] + x3.w*wiF_r[15];
            }
        }
        // waves 2,3 have nothing post-S1 -> they loop and poll t+1 early
    }

    // epilogue: poll r_TT (parity 0, tag TT), stage, emit out[TT-1]
    {
        const unsigned long long* s0 =
            rtag + (size_t)gb * HH + wid * 64 + lane;   // parity 0
        unsigned long long v0, v1;
        const unsigned int tg = (unsigned int)TT;
        do {
            v0 = __hip_atomic_load(s0,      __ATOMIC_RELAXED, __HIP_MEMORY_SCOPE_AGENT);
            v1 = __hip_atomic_load(s0 + HH, __ATOMIC_RELAXED, __HIP_MEMORY_SCOPE_AGENT);
        } while ((unsigned int)(v0 >> 32) != tg || (unsigned int)(v1 >> 32) != tg);
        rlds[0][0][wid * 64 + lane] = __uint_as_float((unsigned int)v0);
        rlds[0][1][wid * 64 + lane] = __uint_as_float((unsigned int)v1);
    }
    __syncthreads();
    if (wid == 4 || wid == 5) {
        const int b = wid - 4;
        float acc0=0.f,acc1=0.f,acc2=0.f,acc3=0.f,acc4=0.f,acc5=0.f,acc6=0.f,acc7=0.f;
        #pragma unroll
        for (int m = 0; m < 8; ++m) {
            float rv = rlds[0][b][lane + 64 * m];
            acc0 += rv * wo_r[m][0]; acc1 += rv * wo_r[m][1];
            acc2 += rv * wo_r[m][2]; acc3 += rv * wo_r[m][3];
            acc4 += rv * wo_r[m][4]; acc5 += rv * wo_r[m][5];
            acc6 += rv * wo_r[m][6]; acc7 += rv * wo_r[m][7];
        }
        float res = 0.f;
        #define RED_(A, O) { float v_ = A; \
            v_ += __shfl_xor(v_, 1);  v_ += __shfl_xor(v_, 2); \
            v_ += __shfl_xor(v_, 4);  v_ += __shfl_xor(v_, 8); \
            v_ += __shfl_xor(v_, 16); v_ += __shfl_xor(v_, 32); \
            if (lane == O) res = v_; }
        RED_(acc0, 0) RED_(acc1, 1) RED_(acc2, 2) RED_(acc3, 3)
        RED_(acc4, 4) RED_(acc5, 5) RED_(acc6, 6) RED_(acc7, 7)
        #undef RED_
        if (lane < 8)
            out[((size_t)(gb + b) * TT + (TT - 1)) * OO + lane] = res;
    }
}

extern "C" void kernel_launch(void* const* d_in, const int* in_sizes, int n_in,
                              void* d_out, int out_size, void* d_ws, size_t ws_size,
                              hipStream_t stream) {
    const float* x     = (const float*)d_in[0];
    const float* noise = (const float*)d_in[1];
    const float* wi    = (const float*)d_in[2];
    const float* si    = (const float*)d_in[3];
    const float* wrec  = (const float*)d_in[4];
    const float* wo    = (const float*)d_in[5];
    const float* so    = (const float*)d_in[6];
    const float* h0    = (const float*)d_in[7];
    float* out = (float*)d_out;
    unsigned long long* rtag = (unsigned long long*)d_ws;   // 512 KB

    (void)in_sizes; (void)n_in; (void)out_size; (void)ws_size;

    void* args[] = {(void*)&x, (void*)&noise, (void*)&wi, (void*)&si,
                    (void*)&wrec, (void*)&wo, (void*)&so, (void*)&h0,
                    (void*)&out, (void*)&rtag};
    hipLaunchCooperativeKernel((void*)rnn_kernel, dim3(NBLOCKS), dim3(NTHREADS),
                               args, 0, stream);
}